// Round 1
// 76.864 us; speedup vs baseline: 1.0062x; 1.0062x over previous
//
#include <hip/hip_runtime.h>
#include <math.h>

#define Bq 512
#define Dq 256

__device__ __forceinline__ float waveReduceSum(float v) {
    #pragma unroll
    for (int off = 32; off > 0; off >>= 1)
        v += __shfl_xor(v, off, 64);
    return v;
}

// Kernel 1: per-row L2 normalize, write transposed fT[k*Bq + i] and coef rows:
//   A1 = a, A2 = a^2, C1 = a*(1+a^3), C2 = (1+a^3)^2
__global__ __launch_bounds__(256) void prep_kernel(
        const float* __restrict__ feat,
        float* __restrict__ fT, float* __restrict__ C1, float* __restrict__ C2,
        float* __restrict__ A1, float* __restrict__ A2) {
    int i = blockIdx.x;
    int k = threadIdx.x;
    float x = feat[i * Dq + k];
    float ss = waveReduceSum(x * x);
    __shared__ float wsum[4];
    int wid = threadIdx.x >> 6, lane = threadIdx.x & 63;
    if (lane == 0) wsum[wid] = ss;
    __syncthreads();
    float tot = wsum[0] + wsum[1] + wsum[2] + wsum[3];
    float n = fmaxf(sqrtf(tot), 1e-12f);
    float a = x / n;
    float a2 = a * a;
    float a3 = a2 * a;
    float c0 = 1.0f + a3;
    fT[k * Bq + i] = a;
    A1[i * Dq + k] = a;
    A2[i * Dq + k] = a2;
    C1[i * Dq + k] = a * c0;
    C2[i * Dq + k] = c0 * c0;
}

// Kernel 2 (restructured for occupancy): block per i, 512 threads (8 waves),
// thread t owns j = t.  4096 waves total = 4 waves/SIMD (was 2).
// k-loop in 8-deep batches: 8 global loads issued up front per chunk so the
// L2-hit latency (~200 cyc) overlaps the 8x7 VALU ops; coefs broadcast from LDS.
__global__ __launch_bounds__(512) void pair_kernel(
        const float* __restrict__ fT,
        const float* __restrict__ C1, const float* __restrict__ C2,
        const float* __restrict__ A1, const float* __restrict__ A2,
        float* __restrict__ Sv, float* __restrict__ Vv) {
    const int i = blockIdx.x;
    const int t = threadIdx.x;   // t == j

    __shared__ __align__(16) float s_c1[Dq];
    __shared__ __align__(16) float s_c2[Dq];
    __shared__ __align__(16) float s_a1[Dq];
    __shared__ __align__(16) float s_a2[Dq];
    if (t < Dq) {
        s_c1[t] = C1[i * Dq + t];
        s_c2[t] = C2[i * Dq + t];
        s_a1[t] = A1[i * Dq + t];
        s_a2[t] = A2[i * Dq + t];
    }
    __syncthreads();

    float du = 0.f, nu = 0.f, dv = 0.f, nv = 0.f;
    const float* __restrict__ bp = fT + t;

    #pragma unroll 2
    for (int k0 = 0; k0 < Dq; k0 += 8) {
        // batch the 8 global loads so they're all in flight before the math
        float b[8];
        #pragma unroll
        for (int u = 0; u < 8; ++u) b[u] = bp[(k0 + u) * Bq];

        float4 q1a = *(const float4*)(s_c1 + k0), q1b = *(const float4*)(s_c1 + k0 + 4);
        float4 q2a = *(const float4*)(s_c2 + k0), q2b = *(const float4*)(s_c2 + k0 + 4);
        float4 q3a = *(const float4*)(s_a1 + k0), q3b = *(const float4*)(s_a1 + k0 + 4);
        float4 q4a = *(const float4*)(s_a2 + k0), q4b = *(const float4*)(s_a2 + k0 + 4);
        const float c1[8] = {q1a.x, q1a.y, q1a.z, q1a.w, q1b.x, q1b.y, q1b.z, q1b.w};
        const float c2[8] = {q2a.x, q2a.y, q2a.z, q2a.w, q2b.x, q2b.y, q2b.z, q2b.w};
        const float a1[8] = {q3a.x, q3a.y, q3a.z, q3a.w, q3b.x, q3b.y, q3b.z, q3b.w};
        const float a2[8] = {q4a.x, q4a.y, q4a.z, q4a.w, q4b.x, q4b.y, q4b.z, q4b.w};

        #pragma unroll
        for (int u = 0; u < 8; ++u) {
            float b1 = b[u];
            float bb = b1 * b1;
            float w  = fmaf(a2[u], b1, 1.0f);
            float wb = w * b1;
            du = fmaf(c1[u], b1, du);
            nu = fmaf(c2[u], bb, nu);
            dv = fmaf(a1[u], wb, dv);
            nv = fmaf(wb,    wb, nv);
        }
    }

    const float Tinv = 1.0f / 0.07f;
    float raw_s = du / fmaxf(sqrtf(nu), 1e-12f) * Tinv;
    float raw_o = dv / fmaxf(sqrtf(nv), 1e-12f) * Tinv;

    float sS = raw_s;                      // diagonal included in S
    float sV = (t == i) ? 0.f : (expf(raw_s) + 3.0f * expf(raw_o));

    sS = waveReduceSum(sS);
    sV = waveReduceSum(sV);
    __shared__ float redS[8], redV[8];
    int wid = t >> 6, lane = t & 63;
    if (lane == 0) { redS[wid] = sS; redV[wid] = sV; }
    __syncthreads();
    if (t == 0) {
        float S = 0.f, V = 0.f;
        #pragma unroll
        for (int w2 = 0; w2 < 8; ++w2) { S += redS[w2]; V += redV[w2]; }
        Sv[i] = S;
        Vv[i] = V;
    }
}

// Kernel 3: loss = -(1/B) * sum_i ( S[i]/B - log(V[i]) )
__global__ __launch_bounds__(512) void final_kernel(
        const float* __restrict__ Sv, const float* __restrict__ Vv,
        float* __restrict__ out) {
    int i = threadIdx.x;
    float t = Sv[i] * (1.0f / Bq) - logf(Vv[i]);
    t = waveReduceSum(t);
    __shared__ float red[8];
    int wid = i >> 6, lane = i & 63;
    if (lane == 0) red[wid] = t;
    __syncthreads();
    if (i == 0) {
        float s = 0.f;
        #pragma unroll
        for (int w = 0; w < 8; ++w) s += red[w];
        out[0] = -s / (float)Bq;
    }
}

extern "C" void kernel_launch(void* const* d_in, const int* in_sizes, int n_in,
                              void* d_out, int out_size, void* d_ws, size_t ws_size,
                              hipStream_t stream) {
    const float* feat = (const float*)d_in[0];
    float* ws = (float*)d_ws;
    float* fT = ws;                 // Dq*Bq
    float* C1 = fT + Bq * Dq;       // Bq*Dq
    float* C2 = C1 + Bq * Dq;
    float* A1 = C2 + Bq * Dq;
    float* A2 = A1 + Bq * Dq;
    float* Sv = A2 + Bq * Dq;       // Bq
    float* Vv = Sv + Bq;            // Bq

    prep_kernel<<<Bq, Dq, 0, stream>>>(feat, fT, C1, C2, A1, A2);
    pair_kernel<<<Bq, 512, 0, stream>>>(fT, C1, C2, A1, A2, Sv, Vv);
    final_kernel<<<1, Bq, 0, stream>>>(Sv, Vv, (float*)d_out);
}